// Round 3
// baseline (1053.644 us; speedup 1.0000x reference)
//
#include <hip/hip_runtime.h>
#include <hip/hip_cooperative_groups.h>

namespace cg = cooperative_groups;

#define GRID 64
#define N_VOX (GRID * GRID * GRID)   // 262144
#define NCH 64
#define NBLK 1024                    // 4 blocks/CU x 256 CUs (co-resident)
#define TPB 256
#define NTHR (NBLK * TPB)            // 262144 threads
#define TILES_PER_BLK (N_VOX / 16 / NBLK)   // 16 gather tiles per block
#define IDX_CAP 2048

// ============================================================================
// ONE cooperative persistent kernel:
//   P0 zero counts -> P1 hist(+rank) -> P2 scan (block/grid/write) ->
//   P3 scatter (atomic-free) -> P4 gather (LDS-staged indices)
// ============================================================================

typedef float f32x4 __attribute__((ext_vector_type(4)));
typedef int   i32x4 __attribute__((ext_vector_type(4)));

__device__ __forceinline__ int vox_of(int x, int y, int z) {
    return ((x >> 2) << 12) | ((y >> 2) << 6) | (z >> 2);
}

__device__ __forceinline__ float4 max4(float4 a, float4 b) {
    float4 r;
    r.x = fmaxf(a.x, b.x); r.y = fmaxf(a.y, b.y);
    r.z = fmaxf(a.z, b.z); r.w = fmaxf(a.w, b.w);
    return r;
}

// non-temporal helpers (read-once / write-once data: keep it out of L2)
__device__ __forceinline__ float4 ntload4(const float4* p) {
    f32x4 v = __builtin_nontemporal_load((const f32x4*)p);
    return make_float4(v[0], v[1], v[2], v[3]);
}
__device__ __forceinline__ void ntstore4(float4* p, float4 v) {
    f32x4 t; t[0] = v.x; t[1] = v.y; t[2] = v.z; t[3] = v.w;
    __builtin_nontemporal_store(t, (f32x4*)p);
}
__device__ __forceinline__ int4 ntload_i4(const int4* p) {
    i32x4 v = __builtin_nontemporal_load((const i32x4*)p);
    return make_int4(v[0], v[1], v[2], v[3]);
}

__global__ void __launch_bounds__(TPB, 4)
k_fused(const int* __restrict__ verts, const float4* __restrict__ feats4,
        float4* __restrict__ out4,
        int* __restrict__ vox, int* __restrict__ rank,
        int* __restrict__ sorted_idx, int* __restrict__ counts,
        int* __restrict__ gstart, int* __restrict__ partial,
        int* __restrict__ pbase, int n) {
    cg::grid_group gg = cg::this_grid();
    const int B    = blockIdx.x;
    const int t    = threadIdx.x;
    const int gtid = B * TPB + t;          // 0 .. NTHR-1
    const int lane = t & 63;
    const int wid  = t >> 6;               // 0..3

    __shared__ int sh_wb[4];
    __shared__ int sh_sst[17];
    __shared__ int sh_sidx[IDX_CAP];

    // ---- P0: zero counts (NTHR == N_VOX) --------------------------------
    counts[gtid] = 0;
    gg.sync();

    // ---- P1: hist — voxel id + in-voxel rank, 4 pts/thread, grid-stride -
    for (int q = gtid; q * 4 < n; q += NTHR) {
        int p0 = q * 4;
        if (p0 + 4 <= n) {
            const int4* v4 = (const int4*)verts;
            int4 a = ntload_i4(&v4[3 * q + 0]);
            int4 b = ntload_i4(&v4[3 * q + 1]);
            int4 c = ntload_i4(&v4[3 * q + 2]);
            int w0 = vox_of(a.x, a.y, a.z);
            int w1 = vox_of(a.w, b.x, b.y);
            int w2 = vox_of(b.z, b.w, c.x);
            int w3 = vox_of(c.y, c.z, c.w);
            ((int4*)vox)[q] = make_int4(w0, w1, w2, w3);
            int r0 = atomicAdd(&counts[w0], 1);
            int r1 = atomicAdd(&counts[w1], 1);
            int r2 = atomicAdd(&counts[w2], 1);
            int r3 = atomicAdd(&counts[w3], 1);
            ((int4*)rank)[q] = make_int4(r0, r1, r2, r3);
        } else {
            for (int p = p0; p < n; p++) {
                int w = vox_of(verts[3 * p], verts[3 * p + 1], verts[3 * p + 2]);
                vox[p]  = w;
                rank[p] = atomicAdd(&counts[w], 1);
            }
        }
    }
    gg.sync();

    // ---- P2a: block-local exclusive scan of this block's 256 counts -----
    int lex;   // thread's block-local exclusive prefix (kept in register)
    {
        int v    = counts[gtid];
        int incl = v;
        #pragma unroll
        for (int off = 1; off < 64; off <<= 1) {
            int u = __shfl_up(incl, off);
            if (lane >= off) incl += u;
        }
        if (lane == 63) sh_wb[wid] = incl;
        __syncthreads();
        int wexcl = 0;
        for (int i = 0; i < wid; i++) wexcl += sh_wb[i];
        lex = wexcl + incl - v;
        if (t == 0) partial[B] = sh_wb[0] + sh_wb[1] + sh_wb[2] + sh_wb[3];
    }
    gg.sync();

    // ---- P2b: block 0 scans the NBLK partials ---------------------------
    if (B == 0) {
        int4 p = ((const int4*)partial)[t];          // 4 partials/thread
        int s  = p.x + p.y + p.z + p.w;
        int incl = s;
        #pragma unroll
        for (int off = 1; off < 64; off <<= 1) {
            int u = __shfl_up(incl, off);
            if (lane >= off) incl += u;
        }
        if (lane == 63) sh_wb[wid] = incl;
        __syncthreads();
        int wexcl = 0;
        for (int i = 0; i < wid; i++) wexcl += sh_wb[i];
        int base = wexcl + incl - s;                 // exclusive for quad
        int4 e;
        e.x = base;
        e.y = base + p.x;
        e.z = e.y  + p.y;
        e.w = e.z  + p.z;
        ((int4*)pbase)[t] = e;
        if (t == TPB - 1) gstart[N_VOX] = base + s;  // grand-total sentinel
    }
    gg.sync();

    // ---- P2c: publish gstart --------------------------------------------
    gstart[gtid] = pbase[B] + lex;
    gg.sync();

    // ---- P3: scatter point indices, atomic-free, 4 pts/thread -----------
    for (int q = gtid; q * 4 < n; q += NTHR) {
        int p0 = q * 4;
        if (p0 + 4 <= n) {
            int4 w = ((const int4*)vox)[q];
            int4 r = ((const int4*)rank)[q];
            sorted_idx[gstart[w.x] + r.x] = p0 + 0;
            sorted_idx[gstart[w.y] + r.y] = p0 + 1;
            sorted_idx[gstart[w.z] + r.z] = p0 + 2;
            sorted_idx[gstart[w.w] + r.w] = p0 + 3;
        } else {
            for (int p = p0; p < n; p++)
                sorted_idx[gstart[vox[p]] + rank[p]] = p;
        }
    }
    gg.sync();

    // ---- P4: gather max — 16 voxels/tile, LDS idx, exact load count -----
    const int g   = t >> 4;        // voxel within tile 0..15
    const int sub = t & 15;        // channel quad
    for (int it = 0; it < TILES_PER_BLK; ++it) {
        int vox0 = (B * TILES_PER_BLK + it) * 16;
        __syncthreads();                       // LDS safe to overwrite
        if (t < 17) sh_sst[t] = gstart[vox0 + t];
        __syncthreads();

        int bstart = sh_sst[0];
        int span   = sh_sst[16] - bstart;
        bool fits  = (span <= IDX_CAP);
        if (fits) {
            for (int i = t; i < span; i += TPB)
                sh_sidx[i] = sorted_idx[bstart + i];
        }
        __syncthreads();

        int s0  = sh_sst[g];
        int cnt = sh_sst[g + 1] - s0;
        float4* outp = &out4[(size_t)(vox0 + g) * 16 + sub];

        if (cnt == 0) {
            ntstore4(outp, make_float4(0.f, 0.f, 0.f, 0.f));
            continue;                           // rejoins at next tile's sync
        }

        int off = s0 - bstart;
        float4 a0 = make_float4(-INFINITY, -INFINITY, -INFINITY, -INFINITY);
        float4 a1 = a0, a2 = a0, a3 = a0;

        int j = 0;
        for (; j + 4 <= cnt; j += 4) {
            int p0, p1, p2, p3;
            if (fits) {
                p0 = sh_sidx[off + j];     p1 = sh_sidx[off + j + 1];
                p2 = sh_sidx[off + j + 2]; p3 = sh_sidx[off + j + 3];
            } else {
                p0 = sorted_idx[s0 + j];     p1 = sorted_idx[s0 + j + 1];
                p2 = sorted_idx[s0 + j + 2]; p3 = sorted_idx[s0 + j + 3];
            }
            a0 = max4(a0, ntload4(&feats4[(size_t)p0 * 16 + sub]));
            a1 = max4(a1, ntload4(&feats4[(size_t)p1 * 16 + sub]));
            a2 = max4(a2, ntload4(&feats4[(size_t)p2 * 16 + sub]));
            a3 = max4(a3, ntload4(&feats4[(size_t)p3 * 16 + sub]));
        }
        for (; j < cnt; j++) {                  // exact scalar tail (<=3)
            int p = fits ? sh_sidx[off + j] : sorted_idx[s0 + j];
            a0 = max4(a0, ntload4(&feats4[(size_t)p * 16 + sub]));
        }
        ntstore4(outp, max4(max4(a0, a1), max4(a2, a3)));
    }
}

// ============================================================================
extern "C" void kernel_launch(void* const* d_in, const int* in_sizes, int n_in,
                              void* d_out, int out_size, void* d_ws, size_t ws_size,
                              hipStream_t stream) {
    const int*    verts  = (const int*)d_in[0];    // [N,3] int32
    const float4* feats4 = (const float4*)d_in[1]; // [N,64] fp32 as [N,16] f4
    float4*       out4   = (float4*)d_out;         // [N_VOX,16] f4

    int n_pts = in_sizes[0] / 3;                   // 1,000,000

    char* w = (char*)d_ws;
    int* vox        = (int*)w;   w += (size_t)n_pts * 4;
    int* rank       = (int*)w;   w += (size_t)n_pts * 4;
    int* sorted_idx = (int*)w;   w += (size_t)n_pts * 4;
    int* counts     = (int*)w;   w += (size_t)N_VOX * 4;
    int* gstart     = (int*)w;   w += (size_t)(N_VOX + 4) * 4;
    int* partial    = (int*)w;   w += (size_t)NBLK * 4;
    int* pbase      = (int*)w;   w += (size_t)NBLK * 4;

    void* args[] = {
        (void*)&verts, (void*)&feats4, (void*)&out4,
        (void*)&vox, (void*)&rank, (void*)&sorted_idx,
        (void*)&counts, (void*)&gstart, (void*)&partial, (void*)&pbase,
        (void*)&n_pts
    };
    hipLaunchCooperativeKernel((void*)k_fused, dim3(NBLK), dim3(TPB),
                               args, 0, stream);
}

// Round 4
// 491.728 us; speedup vs baseline: 2.1427x; 2.1427x over previous
//
#include <hip/hip_runtime.h>

#define GRID 64
#define N_VOX (GRID * GRID * GRID)   // 262144
#define NCH 64
#define NCHUNK 256                   // scan chunks (1024 counts each)

// ============================================================================
// Pipeline: hist(+rank) -> scan(single kernel, decoupled lookback) ->
//           scatter_FEATURES (random writes, fire-and-forget) ->
//           seg_max (pure streaming reads, no indirection)
// Rationale (r3 counters): pipeline is latency-bound (VALUBusy 2.9%, HBM 4.6%).
// Scattered WRITES hide latency; gathered READS expose it. So sort the 256MB
// feature payload itself, then reduce it with sequential reads.
// ============================================================================

typedef float f32x4 __attribute__((ext_vector_type(4)));
typedef int   i32x4 __attribute__((ext_vector_type(4)));

__device__ __forceinline__ int vox_of(int x, int y, int z) {
    return ((x >> 2) << 12) | ((y >> 2) << 6) | (z >> 2);
}

__device__ __forceinline__ float4 max4(float4 a, float4 b) {
    float4 r;
    r.x = fmaxf(a.x, b.x); r.y = fmaxf(a.y, b.y);
    r.z = fmaxf(a.z, b.z); r.w = fmaxf(a.w, b.w);
    return r;
}

__device__ __forceinline__ float4 ntload4(const float4* p) {
    f32x4 v = __builtin_nontemporal_load((const f32x4*)p);
    return make_float4(v[0], v[1], v[2], v[3]);
}
__device__ __forceinline__ void ntstore4(float4* p, float4 v) {
    f32x4 t; t[0] = v.x; t[1] = v.y; t[2] = v.z; t[3] = v.w;
    __builtin_nontemporal_store(t, (f32x4*)p);
}
__device__ __forceinline__ int4 ntload_i4(const int4* p) {
    i32x4 v = __builtin_nontemporal_load((const i32x4*)p);
    return make_int4(v[0], v[1], v[2], v[3]);
}

// ---- k1: voxel id + in-voxel rank per point + histogram, 4 pts/thread ---
__global__ void k_hist(const int* __restrict__ verts, int* __restrict__ vox,
                       int* __restrict__ rank, int* __restrict__ counts, int n) {
    int t  = blockIdx.x * blockDim.x + threadIdx.x;
    int p0 = t * 4;
    if (p0 >= n) return;

    if (p0 + 4 <= n) {
        const int4* v4 = (const int4*)verts;
        int4 a = ntload_i4(&v4[3 * t + 0]);
        int4 b = ntload_i4(&v4[3 * t + 1]);
        int4 c = ntload_i4(&v4[3 * t + 2]);
        int w0 = vox_of(a.x, a.y, a.z);
        int w1 = vox_of(a.w, b.x, b.y);
        int w2 = vox_of(b.z, b.w, c.x);
        int w3 = vox_of(c.y, c.z, c.w);
        ((int4*)vox)[t] = make_int4(w0, w1, w2, w3);
        int r0 = atomicAdd(&counts[w0], 1);
        int r1 = atomicAdd(&counts[w1], 1);
        int r2 = atomicAdd(&counts[w2], 1);
        int r3 = atomicAdd(&counts[w3], 1);
        ((int4*)rank)[t] = make_int4(r0, r1, r2, r3);
    } else {
        for (int p = p0; p < n; p++) {
            int w = vox_of(verts[3 * p], verts[3 * p + 1], verts[3 * p + 2]);
            vox[p]  = w;
            rank[p] = atomicAdd(&counts[w], 1);
        }
    }
}

// ---- k2: full exclusive scan in ONE kernel (decoupled lookback) --------
// 256 blocks x 256 threads; block (by ticket) b scans counts[b*1024 .. +1024)
// state[b]: hi32 = flag (0 none, 1 aggregate, 2 inclusive-prefix), lo32 = value
__global__ void __launch_bounds__(256)
k_scan(const int* __restrict__ counts, int* __restrict__ gstart,
       unsigned long long* __restrict__ state, int* __restrict__ ticket) {
    __shared__ int s_ticket;
    __shared__ int wbase[4];
    __shared__ int s_base;

    if (threadIdx.x == 0) s_ticket = atomicAdd(ticket, 1);
    __syncthreads();
    const int b    = s_ticket;          // chunk id, in scheduling order
    const int t    = threadIdx.x;
    const int lane = t & 63;
    const int wid  = t >> 6;

    int4 c = ((const int4*)counts)[b * 256 + t];
    int s = c.x + c.y + c.z + c.w;

    int incl = s;
    #pragma unroll
    for (int off = 1; off < 64; off <<= 1) {
        int u = __shfl_up(incl, off);
        if (lane >= off) incl += u;
    }
    if (lane == 63) wbase[wid] = incl;
    __syncthreads();

    if (wid == 0) {
        int agg = wbase[0] + wbase[1] + wbase[2] + wbase[3];
        if (lane == 0) {
            __hip_atomic_store(&state[b], (1ULL << 32) | (unsigned)agg,
                               __ATOMIC_RELEASE, __HIP_MEMORY_SCOPE_AGENT);
        }
        // wave-parallel lookback: 64 predecessors per round
        int excl = 0;
        int p_hi = b - 1;
        while (p_hi >= 0) {
            int p = p_hi - lane;
            unsigned long long v;
            do {
                v = (p >= 0)
                  ? __hip_atomic_load(&state[p], __ATOMIC_ACQUIRE,
                                      __HIP_MEMORY_SCOPE_AGENT)
                  : (2ULL << 32);               // virtual terminator, value 0
            } while (__any((int)((v >> 32) == 0)));
            unsigned long long m = __ballot((int)((v >> 32) == 2));
            int cut = m ? (__ffsll((long long)m) - 1) : 64;
            int contrib = (lane <= cut) ? (int)(unsigned)v : 0;
            #pragma unroll
            for (int o = 32; o; o >>= 1) contrib += __shfl_down(contrib, o);
            excl += __shfl(contrib, 0);
            if (m) break;
            p_hi -= 64;
        }
        if (lane == 0) {
            int agg2 = wbase[0] + wbase[1] + wbase[2] + wbase[3];
            __hip_atomic_store(&state[b], (2ULL << 32) | (unsigned)(excl + agg2),
                               __ATOMIC_RELEASE, __HIP_MEMORY_SCOPE_AGENT);
            s_base = excl;
            if (b == NCHUNK - 1) gstart[N_VOX] = excl + agg2;   // sentinel
        }
    }
    __syncthreads();

    int wexcl = 0;
    for (int i = 0; i < wid; i++) wexcl += wbase[i];
    int base = s_base + wexcl + (incl - s);
    int4 g;
    g.x = base;
    g.y = base + c.x;
    g.z = base + c.x + c.y;
    g.w = base + c.x + c.y + c.z;
    ((int4*)gstart)[b * 256 + t] = g;
}

// ---- k3: scatter FEATURE ROWS into sorted order ------------------------
// 16 lanes per point-slot; a 4-group cluster covers 16 consecutive points.
// Iteration i: wave reads points {base+4i .. base+4i+3} = 1KB contiguous.
// Writes: 256B contiguous per point at a random slot — fire-and-forget.
__global__ void __launch_bounds__(256)
k_scatter_feat(const int* __restrict__ vox, const int* __restrict__ rank,
               const int* __restrict__ gstart,
               const float4* __restrict__ feats4,
               float4* __restrict__ sfeat4, int n) {
    int t   = blockIdx.x * 256 + threadIdx.x;
    int grp = t >> 4;                 // global 16-lane group id
    int sub = t & 15;                 // channel quad
    int gw  = grp & ~3;               // cluster base group
    int gl  = grp & 3;                // group within cluster
    int pbase = gw * 4 + gl;          // this group's first point

    #pragma unroll
    for (int i = 0; i < 4; i++) {
        int p = pbase + i * 4;
        if (p >= n) break;
        float4 f = ntload4(&feats4[(size_t)p * 16 + sub]);
        int dst = gstart[vox[p]] + rank[p];   // L2-resident lookups
        sfeat4[(size_t)dst * 16 + sub] = f;
    }
}

// ---- k4: segmented max over CONTIGUOUS sorted feature rows -------------
// 16 lanes per voxel; voxel rows are contiguous => pure streaming reads.
__global__ void __launch_bounds__(256)
k_seg_max(const int* __restrict__ gstart,
          const float4* __restrict__ sfeat4,
          float4* __restrict__ out4) {
    int t   = blockIdx.x * 256 + threadIdx.x;
    int v   = t >> 4;                 // voxel id
    int sub = t & 15;                 // channel quad

    int s0 = gstart[v];
    int s1 = gstart[v + 1];

    float4 a0 = make_float4(-INFINITY, -INFINITY, -INFINITY, -INFINITY);
    float4 a1 = a0;
    int s = s0;
    for (; s + 2 <= s1; s += 2) {
        a0 = max4(a0, sfeat4[(size_t)s       * 16 + sub]);
        a1 = max4(a1, sfeat4[(size_t)(s + 1) * 16 + sub]);
    }
    if (s < s1)
        a0 = max4(a0, sfeat4[(size_t)s * 16 + sub]);

    float4 r = (s1 > s0) ? max4(a0, a1)
                         : make_float4(0.f, 0.f, 0.f, 0.f);
    ntstore4(&out4[(size_t)v * 16 + sub], r);
}

// ============================================================================
extern "C" void kernel_launch(void* const* d_in, const int* in_sizes, int n_in,
                              void* d_out, int out_size, void* d_ws, size_t ws_size,
                              hipStream_t stream) {
    const int*   verts = (const int*)d_in[0];    // [N,3] int32
    const float* feats = (const float*)d_in[1];  // [N,64] fp32
    float*       out   = (float*)d_out;          // [N_VOX*64] fp32

    const int n_pts = in_sizes[0] / 3;           // 1,000,000

    char* w = (char*)d_ws;
    float4* sfeat4   = (float4*)w;           w += (size_t)n_pts * NCH * 4; // 256MB
    int*  vox        = (int*)w;              w += (size_t)n_pts * 4;
    int*  rank       = (int*)w;              w += (size_t)n_pts * 4;
    // --- zeroed region: counts | state | ticket (one memset) ---
    int*  counts     = (int*)w;              w += (size_t)N_VOX * 4;
    unsigned long long* state = (unsigned long long*)w;  w += (size_t)NCHUNK * 8;
    int*  ticket     = (int*)w;              w += 16;
    const size_t zero_bytes = (size_t)N_VOX * 4 + (size_t)NCHUNK * 8 + 16;
    // --- end zeroed region ---
    int*  gstart     = (int*)w;              w += (size_t)(N_VOX + 4) * 4;

    hipMemsetAsync(counts, 0, zero_bytes, stream);

    {   // histogram + voxel ids + in-voxel ranks (4 points/thread)
        const int block = 256;
        const int nthr  = (n_pts + 3) / 4;
        const int grid  = (nthr + block - 1) / block;
        k_hist<<<grid, block, 0, stream>>>(verts, vox, rank, counts, n_pts);
    }
    // full exclusive scan -> gstart[N_VOX+1], single kernel
    k_scan<<<NCHUNK, 256, 0, stream>>>(counts, gstart, state, ticket);

    {   // scatter feature rows into sorted order
        const int clusters = (n_pts + 15) / 16;      // 16 points per cluster
        const long long threads = (long long)clusters * 64;  // 4 groups x 16
        const int grid = (int)((threads + 255) / 256);
        k_scatter_feat<<<grid, 256, 0, stream>>>(vox, rank, gstart,
                                                 (const float4*)feats,
                                                 sfeat4, n_pts);
    }
    {   // segmented max over contiguous rows
        const int grid = (N_VOX * 16) / 256;         // 16384
        k_seg_max<<<grid, 256, 0, stream>>>(gstart, sfeat4, (float4*)out);
    }
}